// Round 5
// baseline (1169.218 us; speedup 1.0000x reference)
//
#include <hip/hip_runtime.h>
#include <math.h>

#define N_NODES 20000
#define T_STEPS 6
#define F_INCH  64
#define HC      256   // gat1: H*C
#define CH      64    // hidden width

__device__ __forceinline__ float fast_tanh(float x){
  float e = __expf(2.f*x);
  return 1.f - 2.f/(e + 1.f);
}

// ---------------- CSR build ----------------
__global__ void k_count(const int* __restrict__ dst, int E, int* __restrict__ deg){
  int e = blockIdx.x*256 + threadIdx.x;
  if (e < E) atomicAdd(&deg[dst[e]], 1);
}

// single block, 1024 threads, 20 elements/thread -> one scan round
__global__ void k_scan(const int* __restrict__ deg, int* __restrict__ row_start, int N){
  __shared__ int wsum[16];
  const int PT = 20;
  int tid = threadIdx.x, wid = tid >> 6, lane = tid & 63;
  int base = tid*PT;
  int loc[PT];
  int s = 0;
  #pragma unroll
  for (int j = 0; j < PT; j++){
    int i = base + j;
    int v = (i < N) ? deg[i] : 0;
    loc[j] = s;            // exclusive local prefix
    s += v;
  }
  int ss = s;
  #pragma unroll
  for (int off = 1; off < 64; off <<= 1){
    int t = __shfl_up(ss, off, 64);
    if (lane >= off) ss += t;
  }
  if (lane == 63) wsum[wid] = ss;
  __syncthreads();
  if (tid < 16){
    int w = wsum[tid];
    #pragma unroll
    for (int off = 1; off < 16; off <<= 1){
      int t = __shfl_up(w, off, 64);
      if (tid >= off) w += t;
    }
    wsum[tid] = w;
  }
  __syncthreads();
  int pre = ((wid ? wsum[wid-1] : 0)) + (ss - s);   // exclusive prefix of this thread's chunk
  #pragma unroll
  for (int j = 0; j < PT; j++){
    int i = base + j;
    if (i < N) row_start[i] = pre + loc[j];
  }
  if (tid == 0) row_start[N] = wsum[15];
}

__global__ void k_scatter(const int* __restrict__ src, const int* __restrict__ dst, int E,
                          const int* __restrict__ row_start, int* __restrict__ cursor,
                          int* __restrict__ csr){
  int e = blockIdx.x*256 + threadIdx.x;
  if (e < E){
    int d = dst[e];
    int pos = atomicAdd(&cursor[d], 1);
    csr[row_start[d] + pos] = src[e];
  }
}

// wave rank-sort per bucket (deg ~16) -> deterministic CSR
__global__ void k_sort(const int* __restrict__ row_start, int* __restrict__ csr, int N){
  int wid = threadIdx.x >> 6, lane = threadIdx.x & 63;
  int d = blockIdx.x*4 + wid;
  if (d >= N) return;
  int s = row_start[d], e = row_start[d+1], len = e - s;
  if (len <= 1) return;
  if (len <= 64){
    int v = (lane < len) ? csr[s + lane] : 0x7fffffff;
    int rank = 0;
    for (int j = 0; j < len; j++){
      int vj = __shfl(v, j, 64);
      rank += (int)((vj < v) | ((vj == v) & (j < lane)));
    }
    if (lane < len) csr[s + rank] = v;
  } else if (lane == 0){
    for (int i = s+1; i < e; i++){
      int key = csr[i]; int j = i-1;
      while (j >= s && csr[j] > key){ csr[j+1] = csr[j]; j--; }
      csr[j+1] = key;
    }
  }
}

// ---------------- GEMM 64->256 dual, 16 rows/block ----------------
__global__ void k_gemm1(const float* __restrict__ A, int lda,
                        const float* __restrict__ B1, const float* __restrict__ B2,
                        float* __restrict__ C1, float* __restrict__ C2, int M){
  __shared__ float aT[64*20];
  int tid = threadIdx.x;
  int r0 = blockIdx.x*16;
  for (int idx = tid; idx < 16*64; idx += 256){
    int r = idx >> 6, k = idx & 63;
    int row = r0 + r;
    aT[k*20 + r] = (row < M) ? A[(size_t)row*lda + k] : 0.f;
  }
  __syncthreads();
  float acc1[16], acc2[16];
  #pragma unroll
  for (int r = 0; r < 16; r++){ acc1[r] = 0.f; acc2[r] = 0.f; }
  const float4* aT4 = (const float4*)aT;
  #pragma unroll 4
  for (int k = 0; k < 64; k++){
    float b1 = B1[k*256 + tid];
    float b2 = B2[k*256 + tid];
    float4 a0 = aT4[k*5+0], a1 = aT4[k*5+1], a2 = aT4[k*5+2], a3 = aT4[k*5+3];
    float av[16] = {a0.x,a0.y,a0.z,a0.w, a1.x,a1.y,a1.z,a1.w,
                    a2.x,a2.y,a2.z,a2.w, a3.x,a3.y,a3.z,a3.w};
    #pragma unroll
    for (int r = 0; r < 16; r++){
      acc1[r] = fmaf(av[r], b1, acc1[r]);
      acc2[r] = fmaf(av[r], b2, acc2[r]);
    }
  }
  #pragma unroll
  for (int r = 0; r < 16; r++){
    int row = r0 + r;
    if (row < M){
      C1[(size_t)row*256 + tid] = acc1[r];
      C2[(size_t)row*256 + tid] = acc2[r];
    }
  }
}

// ---------------- GEMM 256->64 dual, 16 rows/block ----------------
__global__ void k_gemm2(const float* __restrict__ A,
                        const float* __restrict__ B1, const float* __restrict__ B2,
                        float* __restrict__ C1, float* __restrict__ C2, int M){
  __shared__ float aT[256*20];  // 20KB
  int tid = threadIdx.x;
  int r0 = blockIdx.x*16;
  for (int idx = tid; idx < 16*256; idx += 256){
    int r = idx >> 8, k = idx & 255;
    int row = r0 + r;
    aT[k*20 + r] = (row < M) ? A[(size_t)row*256 + k] : 0.f;
  }
  __syncthreads();
  int u = tid & 63, rq = tid >> 6;
  float acc1[4] = {0,0,0,0}, acc2[4] = {0,0,0,0};
  const float4* aT4 = (const float4*)aT;
  #pragma unroll 4
  for (int k = 0; k < 256; k++){
    float b1 = B1[k*64 + u];
    float b2 = B2[k*64 + u];
    float4 a = aT4[k*5 + rq];
    acc1[0] = fmaf(a.x, b1, acc1[0]); acc2[0] = fmaf(a.x, b2, acc2[0]);
    acc1[1] = fmaf(a.y, b1, acc1[1]); acc2[1] = fmaf(a.y, b2, acc2[1]);
    acc1[2] = fmaf(a.z, b1, acc1[2]); acc2[2] = fmaf(a.z, b2, acc2[2]);
    acc1[3] = fmaf(a.w, b1, acc1[3]); acc2[3] = fmaf(a.w, b2, acc2[3]);
  }
  #pragma unroll
  for (int j = 0; j < 4; j++){
    int row = r0 + rq*4 + j;
    if (row < M){
      C1[(size_t)row*64 + u] = acc1[j];
      C2[(size_t)row*64 + u] = acc2[j];
    }
  }
}

// ---------------- GATv2 layer 1: one wave/dst, float4/lane, 8-deep prefetch ----------------
// All control flow inside a wave is uniform (s0/s1/cnt identical across lanes),
// so the shfl-based index broadcast always executes at full convergence.
__global__ void k_gat1(const float* __restrict__ xl, const float* __restrict__ xr,
                       const int* __restrict__ row_start, const int* __restrict__ csr,
                       const float* __restrict__ att, const float* __restrict__ bias,
                       float* __restrict__ out, int N){
  int wid = threadIdx.x >> 6, lane = threadIdx.x & 63;
  int dst = blockIdx.x*4 + wid;
  if (dst >= N) return;
  const float4* xl4 = (const float4*)xl;
  float4 xr4 = ((const float4*)xr)[(size_t)dst*64 + lane];
  float4 at4 = ((const float4*)att)[lane];
  int s0 = row_start[dst], s1 = row_start[dst+1];
  float m = -INFINITY, den = 0.f, ax = 0.f, ay = 0.f, az = 0.f, aw = 0.f;
  const float4 Z = make_float4(0.f,0.f,0.f,0.f);

  auto STEP = [&](float4 v, bool valid){
    if (!valid) return;                         // wave-uniform predicate
    float tx = v.x + xr4.x; tx = fmaxf(tx, 0.2f*tx);
    float ty = v.y + xr4.y; ty = fmaxf(ty, 0.2f*ty);
    float tz = v.z + xr4.z; tz = fmaxf(tz, 0.2f*tz);
    float tw = v.w + xr4.w; tw = fmaxf(tw, 0.2f*tw);
    float p = fmaf(tx, at4.x, fmaf(ty, at4.y, fmaf(tz, at4.z, tw*at4.w)));
    p += __shfl_xor(p, 1, 64);
    p += __shfl_xor(p, 2, 64);
    p += __shfl_xor(p, 4, 64);
    p += __shfl_xor(p, 8, 64);
    float mn = fmaxf(m, p);
    float sc = __expf(m - mn);
    float w  = __expf(p - mn);
    den = fmaf(den, sc, w);
    ax = fmaf(ax, sc, w*v.x);
    ay = fmaf(ay, sc, w*v.y);
    az = fmaf(az, sc, w*v.z);
    aw = fmaf(aw, sc, w*v.w);
    m = mn;
  };

  for (int base = s0; base < s1; base += 64){
    int rem = s1 - base;
    int cnt = rem < 64 ? rem : 64;
    int idxv = (base + lane < s1) ? csr[base + lane] : 0;
    auto LD = [&](int i)->float4 {              // i is wave-uniform
      int s = __shfl(idxv, i < cnt ? i : 0, 64);
      return (i < cnt) ? xl4[(size_t)s*64 + lane] : Z;
    };
    float4 p0=LD(0), p1=LD(1), p2=LD(2), p3=LD(3);
    float4 p4=LD(4), p5=LD(5), p6=LD(6), p7=LD(7);
    for (int i = 0; i < cnt; i += 4){
      float4 n0=LD(i+8), n1=LD(i+9), n2=LD(i+10), n3=LD(i+11);
      STEP(p0, true);
      STEP(p1, i+1 < cnt);
      STEP(p2, i+2 < cnt);
      STEP(p3, i+3 < cnt);
      p0=p4; p1=p5; p2=p6; p3=p7;
      p4=n0; p5=n1; p6=n2; p7=n3;
    }
  }
  float invd = (s1 > s0) ? 1.f/den : 0.f;
  float4 b4 = ((const float4*)bias)[lane];
  float rx = fmaf(ax, invd, b4.x);
  float ry = fmaf(ay, invd, b4.y);
  float rz = fmaf(az, invd, b4.z);
  float rw = fmaf(aw, invd, b4.w);
  rx = rx > 0.f ? rx : (__expf(rx) - 1.f);
  ry = ry > 0.f ? ry : (__expf(ry) - 1.f);
  rz = rz > 0.f ? rz : (__expf(rz) - 1.f);
  rw = rw > 0.f ? rw : (__expf(rw) - 1.f);
  ((float4*)out)[(size_t)dst*64 + lane] = make_float4(rx, ry, rz, rw);
}

// ---------------- GATv2 layer 2: one wave/dst, 4 edge groups ----------------
// Wave-uniform trip count K; every __shfl executes at full convergence; per-group
// work predicated on group-uniform (e < cnt). No shuffle reads an inactive lane.
__global__ void k_gat2(const float* __restrict__ xl, const float* __restrict__ xr,
                       const int* __restrict__ row_start, const int* __restrict__ csr,
                       const float* __restrict__ att, const float* __restrict__ bias,
                       float* __restrict__ out, int N){
  int wid = threadIdx.x >> 6, lane = threadIdx.x & 63;
  int dst = blockIdx.x*4 + wid;
  if (dst >= N) return;
  int g = lane >> 4, q = lane & 15;
  const float4* xl4 = (const float4*)xl;
  float4 xr4 = ((const float4*)xr)[(size_t)dst*16 + q];
  float4 at4 = ((const float4*)att)[q];
  int s0 = row_start[dst], s1 = row_start[dst+1];
  float m = -INFINITY, den = 0.f, ax = 0.f, ay = 0.f, az = 0.f, aw = 0.f;
  const float4 Z = make_float4(0.f,0.f,0.f,0.f);

  for (int base = s0; base < s1; base += 64){
    int rem = s1 - base;
    int cnt = rem < 64 ? rem : 64;
    int idxv = (base + lane < s1) ? csr[base + lane] : 0;
    int K = (cnt + 3) >> 2;                      // wave-uniform trip count
    int e0 = g, e1 = g + 4;
    int sA = __shfl(idxv, e0 < cnt ? e0 : 0, 64);
    int sB = __shfl(idxv, e1 < cnt ? e1 : 0, 64);
    float4 vA = (e0 < cnt) ? xl4[(size_t)sA*16 + q] : Z;
    float4 vB = (e1 < cnt) ? xl4[(size_t)sB*16 + q] : Z;
    for (int k = 0; k < K; k++){
      int en = 4*k + 8 + g;
      int sN = __shfl(idxv, en < cnt ? en : 0, 64);   // full convergence
      float4 vN = (en < cnt) ? xl4[(size_t)sN*16 + q] : Z;
      int e = 4*k + g;
      if (e < cnt){                                   // group-uniform
        float4 v = vA;
        float tx = v.x + xr4.x; tx = fmaxf(tx, 0.2f*tx);
        float ty = v.y + xr4.y; ty = fmaxf(ty, 0.2f*ty);
        float tz = v.z + xr4.z; tz = fmaxf(tz, 0.2f*tz);
        float tw = v.w + xr4.w; tw = fmaxf(tw, 0.2f*tw);
        float p = fmaf(tx, at4.x, fmaf(ty, at4.y, fmaf(tz, at4.z, tw*at4.w)));
        p += __shfl_xor(p, 1, 64);
        p += __shfl_xor(p, 2, 64);
        p += __shfl_xor(p, 4, 64);
        p += __shfl_xor(p, 8, 64);
        float mn = fmaxf(m, p);
        float sc = __expf(m - mn);
        float w  = __expf(p - mn);
        den = fmaf(den, sc, w);
        ax = fmaf(ax, sc, w*v.x);
        ay = fmaf(ay, sc, w*v.y);
        az = fmaf(az, sc, w*v.z);
        aw = fmaf(aw, sc, w*v.w);
        m = mn;
      }
      vA = vB; vB = vN;
    }
  }
  // merge 4 edge groups (full convergence here)
  float M2 = fmaxf(m, __shfl_xor(m, 16, 64));
  float Mx = fmaxf(M2, __shfl_xor(M2, 32, 64));
  float sc = (m > -INFINITY) ? __expf(m - Mx) : 0.f;
  den *= sc; ax *= sc; ay *= sc; az *= sc; aw *= sc;
  den += __shfl_xor(den, 16, 64); den += __shfl_xor(den, 32, 64);
  ax  += __shfl_xor(ax, 16, 64);  ax  += __shfl_xor(ax, 32, 64);
  ay  += __shfl_xor(ay, 16, 64);  ay  += __shfl_xor(ay, 32, 64);
  az  += __shfl_xor(az, 16, 64);  az  += __shfl_xor(az, 32, 64);
  aw  += __shfl_xor(aw, 16, 64);  aw  += __shfl_xor(aw, 32, 64);
  float invd = (s1 > s0) ? 1.f/den : 0.f;
  float4 b4 = ((const float4*)bias)[q];
  float rx = fmaf(ax, invd, b4.x);
  float ry = fmaf(ay, invd, b4.y);
  float rz = fmaf(az, invd, b4.z);
  float rw = fmaf(aw, invd, b4.w);
  rx = rx > 0.f ? rx : (__expf(rx) - 1.f);
  ry = ry > 0.f ? ry : (__expf(ry) - 1.f);
  rz = rz > 0.f ? rz : (__expf(rz) - 1.f);
  rw = rw > 0.f ? rw : (__expf(rw) - 1.f);
  if (g == 0) ((float4*)out)[(size_t)dst*16 + q] = make_float4(rx, ry, rz, rw);
}

// ---------------- LSTM weight pack: W4[k][u][4gates], biasc[u][4gates] ----------------
__global__ void k_pack(const float* __restrict__ Wih, const float* __restrict__ Whh,
                       const float* __restrict__ bih, const float* __restrict__ bhh,
                       float* __restrict__ Wih4, float* __restrict__ Whh4,
                       float* __restrict__ biasc){
  int idx = blockIdx.x*256 + threadIdx.x;
  if (idx < 64*256){
    int k = idx >> 8, cu = idx & 255;
    int u = cu >> 2, g = cu & 3;
    Wih4[idx] = Wih[(g*64+u)*64 + k];
    Whh4[idx] = Whh[(g*64+u)*64 + k];
  }
  if (idx < 256){
    int u = idx >> 2, g = idx & 3;
    biasc[idx] = bih[g*64+u] + bhh[g*64+u];
  }
}

// ---------------- LSTM: 6 steps fused, 32 rows/block, packed-f4 weights ----------------
// Per k: 2 global b128 (weights, L2-hot, amortized over 32 rows) + 2 LDS b128
// broadcasts + 32 FMA. h lives in LDS across steps, c in registers.
__global__ __launch_bounds__(512) void k_lstm_fused(
    const float* __restrict__ h2_all,                      // [T][N][64]
    const float* __restrict__ Wih4, const float* __restrict__ Whh4,
    const float* __restrict__ biasc,
    float* __restrict__ hlast, int N){
  __shared__ float xT[64*36];   // [k][row(32)+pad4]
  __shared__ float hT[64*36];
  int tid = threadIdx.x;
  int u = tid & 63, rq = tid >> 6;       // rq in 0..7, 4 rows each
  int r0 = blockIdx.x*32;
  for (int idx = tid; idx < 64*36; idx += 512) hT[idx] = 0.f;
  float4 bc = ((const float4*)biasc)[u];
  const float4* Wi4 = (const float4*)Wih4;
  const float4* Wh4 = (const float4*)Whh4;
  const float4* xT4 = (const float4*)xT;
  const float4* hT4 = (const float4*)hT;
  float c[4] = {0,0,0,0};
  float h[4] = {0,0,0,0};
  for (int t = 0; t < T_STEPS; t++){
    const float* xt = h2_all + (size_t)t*N_NODES*CH;
    #pragma unroll
    for (int it = 0; it < 4; it++){
      int idx = tid + it*512;
      int r = idx >> 6, k = idx & 63;
      int row = r0 + r;
      xT[k*36 + r] = (row < N) ? xt[(size_t)row*64 + k] : 0.f;
    }
    __syncthreads();                 // xT staged; hT writes from t-1 visible
    float ai[4], af[4], ag[4], ao[4];
    #pragma unroll
    for (int j = 0; j < 4; j++){ ai[j]=bc.x; af[j]=bc.y; ag[j]=bc.z; ao[j]=bc.w; }
    #pragma unroll 4
    for (int k = 0; k < 64; k++){
      float4 wi = Wi4[k*64 + u];     // 4 gate weights for unit u, input slice k
      float4 wh = Wh4[k*64 + u];
      float4 xq = xT4[k*9 + rq];     // x[k] for this thread's 4 rows (broadcast)
      float4 hq = hT4[k*9 + rq];
      float xv[4] = {xq.x, xq.y, xq.z, xq.w};
      float hv[4] = {hq.x, hq.y, hq.z, hq.w};
      #pragma unroll
      for (int j = 0; j < 4; j++){
        ai[j] = fmaf(xv[j], wi.x, ai[j]); ai[j] = fmaf(hv[j], wh.x, ai[j]);
        af[j] = fmaf(xv[j], wi.y, af[j]); af[j] = fmaf(hv[j], wh.y, af[j]);
        ag[j] = fmaf(xv[j], wi.z, ag[j]); ag[j] = fmaf(hv[j], wh.z, ag[j]);
        ao[j] = fmaf(xv[j], wi.w, ao[j]); ao[j] = fmaf(hv[j], wh.w, ao[j]);
      }
    }
    #pragma unroll
    for (int j = 0; j < 4; j++){
      float I = 1.f/(1.f + __expf(-ai[j]));
      float F = 1.f/(1.f + __expf(-af[j]));
      float O = 1.f/(1.f + __expf(-ao[j]));
      float G = fast_tanh(ag[j]);
      c[j] = fmaf(F, c[j], I*G);
      h[j] = O * fast_tanh(c[j]);
    }
    __syncthreads();                 // all waves done reading hT/xT of step t
    #pragma unroll
    for (int j = 0; j < 4; j++) hT[u*36 + rq*4 + j] = h[j];
    // next iteration's post-staging barrier orders these writes before reads
  }
  #pragma unroll
  for (int j = 0; j < 4; j++){
    int row = r0 + rq*4 + j;
    if (row < N) hlast[(size_t)row*64 + u] = h[j];
  }
}

// ---------------- MLP head (fused) ----------------
__global__ void k_mlp(const float* __restrict__ h, const float* __restrict__ Wfc1,
                      const float* __restrict__ bfc1, const float* __restrict__ Wout,
                      const float* __restrict__ bout, float* __restrict__ out, int N){
  int wid = threadIdx.x >> 6, lane = threadIdx.x & 63;
  int row = blockIdx.x*4 + wid;
  if (row >= N) return;
  int j = lane & 31;
  float acc = bfc1[j];
  const float* hr = &h[(size_t)row*64];
  #pragma unroll 8
  for (int k = 0; k < 64; k++) acc = fmaf(hr[k], Wfc1[k*32 + j], acc);
  acc = fmaxf(acc, 0.f);
  float v = acc * Wout[j];
  #pragma unroll
  for (int off = 1; off < 32; off <<= 1) v += __shfl_xor(v, off, 64);
  if (lane == 0) out[row] = v + bout[0];
}

// ---------------- launch ----------------
extern "C" void kernel_launch(void* const* d_in, const int* in_sizes, int n_in,
                              void* d_out, int out_size, void* d_ws, size_t ws_size,
                              hipStream_t stream){
  const float* x    = (const float*)d_in[0];
  const int*   edge = (const int*)  d_in[1];
  const float* Wl1  = (const float*)d_in[2];
  const float* Wr1  = (const float*)d_in[3];
  const float* att1 = (const float*)d_in[4];
  const float* b1   = (const float*)d_in[5];
  const float* Wl2  = (const float*)d_in[6];
  const float* Wr2  = (const float*)d_in[7];
  const float* att2 = (const float*)d_in[8];
  const float* b2   = (const float*)d_in[9];
  const float* Wih  = (const float*)d_in[10];
  const float* Whh  = (const float*)d_in[11];
  const float* bih  = (const float*)d_in[12];
  const float* bhh  = (const float*)d_in[13];
  const float* Wfc1 = (const float*)d_in[14];
  const float* bfc1 = (const float*)d_in[15];
  const float* Wout = (const float*)d_in[16];
  const float* bout = (const float*)d_in[17];
  float* out = (float*)d_out;

  const int N = N_NODES;
  const int E = in_sizes[1] / 2;

  char* p = (char*)d_ws;
  auto alloc = [&](size_t bytes)->char*{ char* q = p; p += (bytes + 255) & ~(size_t)255; return q; };
  int* csr       = (int*)alloc((size_t)E*sizeof(int));
  int* row_start = (int*)alloc((size_t)(N+1)*sizeof(int));
  int* deg       = (int*)alloc((size_t)N*sizeof(int));
  int* cursor    = (int*)alloc((size_t)N*sizeof(int));
  float* xl1    = (float*)alloc((size_t)N*HC*4);
  float* xr1    = (float*)alloc((size_t)N*HC*4);
  float* h1     = (float*)alloc((size_t)N*HC*4);
  float* h2_all = (float*)alloc((size_t)T_STEPS*N*CH*4);
  float* Wih4   = (float*)alloc(64*256*4);
  float* Whh4   = (float*)alloc(64*256*4);
  float* biasc  = (float*)alloc(256*4);
  float* xl2 = xl1;     // reuse: xl1/xr1 dead once h1 is computed
  float* xr2 = xr1;
  float* hlast = h1;    // reuse: h1 dead after last k_gemm2

  const int* srcIdx = edge;       // edge_index[0]
  const int* dstIdx = edge + E;   // edge_index[1]

  hipMemsetAsync(deg,    0, (size_t)N*4, stream);
  hipMemsetAsync(cursor, 0, (size_t)N*4, stream);

  k_count  <<<(E+255)/256, 256, 0, stream>>>(dstIdx, E, deg);
  k_scan   <<<1, 1024, 0, stream>>>(deg, row_start, N);
  k_scatter<<<(E+255)/256, 256, 0, stream>>>(srcIdx, dstIdx, E, row_start, cursor, csr);
  k_sort   <<<(N+3)/4, 256, 0, stream>>>(row_start, csr, N);
  k_pack   <<<64, 256, 0, stream>>>(Wih, Whh, bih, bhh, Wih4, Whh4, biasc);

  for (int t = 0; t < T_STEPS; t++){
    k_gemm1<<<(N+15)/16, 256, 0, stream>>>(x + t*F_INCH, T_STEPS*F_INCH, Wl1, Wr1, xl1, xr1, N);
    k_gat1 <<<(N+3)/4,   256, 0, stream>>>(xl1, xr1, row_start, csr, att1, b1, h1, N);
    k_gemm2<<<(N+15)/16, 256, 0, stream>>>(h1, Wl2, Wr2, xl2, xr2, N);
    k_gat2 <<<(N+3)/4,   256, 0, stream>>>(xl2, xr2, row_start, csr, att2, b2,
                                           h2_all + (size_t)t*N*CH, N);
  }
  k_lstm_fused<<<(N+31)/32, 512, 0, stream>>>(h2_all, Wih4, Whh4, biasc, hlast, N);
  k_mlp<<<(N+3)/4, 256, 0, stream>>>(hlast, Wfc1, bfc1, Wout, bout, out, N);
}

// Round 6
// 1161.562 us; speedup vs baseline: 1.0066x; 1.0066x over previous
//
#include <hip/hip_runtime.h>
#include <math.h>

#define N_NODES 20000
#define T_STEPS 6
#define F_INCH  64
#define HC      256   // gat1: H*C
#define CH      64    // hidden width

__device__ __forceinline__ float fast_tanh(float x){
  float e = __expf(2.f*x);
  return 1.f - 2.f/(e + 1.f);
}

// ---------------- CSR build ----------------
__global__ void k_count(const int* __restrict__ dst, int E, int* __restrict__ deg){
  int e = blockIdx.x*256 + threadIdx.x;
  if (e < E) atomicAdd(&deg[dst[e]], 1);
}

// single block, 1024 threads, 20 elements/thread -> one scan round
__global__ void k_scan(const int* __restrict__ deg, int* __restrict__ row_start, int N){
  __shared__ int wsum[16];
  const int PT = 20;
  int tid = threadIdx.x, wid = tid >> 6, lane = tid & 63;
  int base = tid*PT;
  int loc[PT];
  int s = 0;
  #pragma unroll
  for (int j = 0; j < PT; j++){
    int i = base + j;
    int v = (i < N) ? deg[i] : 0;
    loc[j] = s;            // exclusive local prefix
    s += v;
  }
  int ss = s;
  #pragma unroll
  for (int off = 1; off < 64; off <<= 1){
    int t = __shfl_up(ss, off, 64);
    if (lane >= off) ss += t;
  }
  if (lane == 63) wsum[wid] = ss;
  __syncthreads();
  if (tid < 16){
    int w = wsum[tid];
    #pragma unroll
    for (int off = 1; off < 16; off <<= 1){
      int t = __shfl_up(w, off, 64);
      if (tid >= off) w += t;
    }
    wsum[tid] = w;
  }
  __syncthreads();
  int pre = ((wid ? wsum[wid-1] : 0)) + (ss - s);   // exclusive prefix of this thread's chunk
  #pragma unroll
  for (int j = 0; j < PT; j++){
    int i = base + j;
    if (i < N) row_start[i] = pre + loc[j];
  }
  if (tid == 0) row_start[N] = wsum[15];
}

__global__ void k_scatter(const int* __restrict__ src, const int* __restrict__ dst, int E,
                          const int* __restrict__ row_start, int* __restrict__ cursor,
                          int* __restrict__ csr){
  int e = blockIdx.x*256 + threadIdx.x;
  if (e < E){
    int d = dst[e];
    int pos = atomicAdd(&cursor[d], 1);
    csr[row_start[d] + pos] = src[e];
  }
}

// wave rank-sort per bucket (deg ~16) -> deterministic CSR
__global__ void k_sort(const int* __restrict__ row_start, int* __restrict__ csr, int N){
  int wid = threadIdx.x >> 6, lane = threadIdx.x & 63;
  int d = blockIdx.x*4 + wid;
  if (d >= N) return;
  int s = row_start[d], e = row_start[d+1], len = e - s;
  if (len <= 1) return;
  if (len <= 64){
    int v = (lane < len) ? csr[s + lane] : 0x7fffffff;
    int rank = 0;
    for (int j = 0; j < len; j++){
      int vj = __shfl(v, j, 64);
      rank += (int)((vj < v) | ((vj == v) & (j < lane)));
    }
    if (lane < len) csr[s + rank] = v;
  } else if (lane == 0){
    for (int i = s+1; i < e; i++){
      int key = csr[i]; int j = i-1;
      while (j >= s && csr[j] > key){ csr[j+1] = csr[j]; j--; }
      csr[j+1] = key;
    }
  }
}

// ---------------- GEMM 64->256 dual, 16 rows/block ----------------
__global__ void k_gemm1(const float* __restrict__ A, int lda,
                        const float* __restrict__ B1, const float* __restrict__ B2,
                        float* __restrict__ C1, float* __restrict__ C2, int M){
  __shared__ float aT[64*20];
  int tid = threadIdx.x;
  int r0 = blockIdx.x*16;
  for (int idx = tid; idx < 16*64; idx += 256){
    int r = idx >> 6, k = idx & 63;
    int row = r0 + r;
    aT[k*20 + r] = (row < M) ? A[(size_t)row*lda + k] : 0.f;
  }
  __syncthreads();
  float acc1[16], acc2[16];
  #pragma unroll
  for (int r = 0; r < 16; r++){ acc1[r] = 0.f; acc2[r] = 0.f; }
  const float4* aT4 = (const float4*)aT;
  #pragma unroll 4
  for (int k = 0; k < 64; k++){
    float b1 = B1[k*256 + tid];
    float b2 = B2[k*256 + tid];
    float4 a0 = aT4[k*5+0], a1 = aT4[k*5+1], a2 = aT4[k*5+2], a3 = aT4[k*5+3];
    float av[16] = {a0.x,a0.y,a0.z,a0.w, a1.x,a1.y,a1.z,a1.w,
                    a2.x,a2.y,a2.z,a2.w, a3.x,a3.y,a3.z,a3.w};
    #pragma unroll
    for (int r = 0; r < 16; r++){
      acc1[r] = fmaf(av[r], b1, acc1[r]);
      acc2[r] = fmaf(av[r], b2, acc2[r]);
    }
  }
  #pragma unroll
  for (int r = 0; r < 16; r++){
    int row = r0 + r;
    if (row < M){
      C1[(size_t)row*256 + tid] = acc1[r];
      C2[(size_t)row*256 + tid] = acc2[r];
    }
  }
}

// ---------------- GEMM 256->64 dual, 16 rows/block ----------------
__global__ void k_gemm2(const float* __restrict__ A,
                        const float* __restrict__ B1, const float* __restrict__ B2,
                        float* __restrict__ C1, float* __restrict__ C2, int M){
  __shared__ float aT[256*20];  // 20KB
  int tid = threadIdx.x;
  int r0 = blockIdx.x*16;
  for (int idx = tid; idx < 16*256; idx += 256){
    int r = idx >> 8, k = idx & 255;
    int row = r0 + r;
    aT[k*20 + r] = (row < M) ? A[(size_t)row*256 + k] : 0.f;
  }
  __syncthreads();
  int u = tid & 63, rq = tid >> 6;
  float acc1[4] = {0,0,0,0}, acc2[4] = {0,0,0,0};
  const float4* aT4 = (const float4*)aT;
  #pragma unroll 4
  for (int k = 0; k < 256; k++){
    float b1 = B1[k*64 + u];
    float b2 = B2[k*64 + u];
    float4 a = aT4[k*5 + rq];
    acc1[0] = fmaf(a.x, b1, acc1[0]); acc2[0] = fmaf(a.x, b2, acc2[0]);
    acc1[1] = fmaf(a.y, b1, acc1[1]); acc2[1] = fmaf(a.y, b2, acc2[1]);
    acc1[2] = fmaf(a.z, b1, acc1[2]); acc2[2] = fmaf(a.z, b2, acc2[2]);
    acc1[3] = fmaf(a.w, b1, acc1[3]); acc2[3] = fmaf(a.w, b2, acc2[3]);
  }
  #pragma unroll
  for (int j = 0; j < 4; j++){
    int row = r0 + rq*4 + j;
    if (row < M){
      C1[(size_t)row*64 + u] = acc1[j];
      C2[(size_t)row*64 + u] = acc2[j];
    }
  }
}

// ---------------- GATv2 layer 1: one wave/dst, float4/lane, 8-deep prefetch ----------------
// All control flow inside a wave is uniform (s0/s1/cnt identical across lanes),
// so the shfl-based index broadcast always executes at full convergence.
__global__ void k_gat1(const float* __restrict__ xl, const float* __restrict__ xr,
                       const int* __restrict__ row_start, const int* __restrict__ csr,
                       const float* __restrict__ att, const float* __restrict__ bias,
                       float* __restrict__ out, int N){
  int wid = threadIdx.x >> 6, lane = threadIdx.x & 63;
  int dst = blockIdx.x*4 + wid;
  if (dst >= N) return;
  const float4* xl4 = (const float4*)xl;
  float4 xr4 = ((const float4*)xr)[(size_t)dst*64 + lane];
  float4 at4 = ((const float4*)att)[lane];
  int s0 = row_start[dst], s1 = row_start[dst+1];
  float m = -INFINITY, den = 0.f, ax = 0.f, ay = 0.f, az = 0.f, aw = 0.f;
  const float4 Z = make_float4(0.f,0.f,0.f,0.f);

  auto STEP = [&](float4 v, bool valid){
    if (!valid) return;                         // wave-uniform predicate
    float tx = v.x + xr4.x; tx = fmaxf(tx, 0.2f*tx);
    float ty = v.y + xr4.y; ty = fmaxf(ty, 0.2f*ty);
    float tz = v.z + xr4.z; tz = fmaxf(tz, 0.2f*tz);
    float tw = v.w + xr4.w; tw = fmaxf(tw, 0.2f*tw);
    float p = fmaf(tx, at4.x, fmaf(ty, at4.y, fmaf(tz, at4.z, tw*at4.w)));
    p += __shfl_xor(p, 1, 64);
    p += __shfl_xor(p, 2, 64);
    p += __shfl_xor(p, 4, 64);
    p += __shfl_xor(p, 8, 64);
    float mn = fmaxf(m, p);
    float sc = __expf(m - mn);
    float w  = __expf(p - mn);
    den = fmaf(den, sc, w);
    ax = fmaf(ax, sc, w*v.x);
    ay = fmaf(ay, sc, w*v.y);
    az = fmaf(az, sc, w*v.z);
    aw = fmaf(aw, sc, w*v.w);
    m = mn;
  };

  for (int base = s0; base < s1; base += 64){
    int rem = s1 - base;
    int cnt = rem < 64 ? rem : 64;
    int idxv = (base + lane < s1) ? csr[base + lane] : 0;
    auto LD = [&](int i)->float4 {              // i is wave-uniform
      int s = __shfl(idxv, i < cnt ? i : 0, 64);
      return (i < cnt) ? xl4[(size_t)s*64 + lane] : Z;
    };
    float4 p0=LD(0), p1=LD(1), p2=LD(2), p3=LD(3);
    float4 p4=LD(4), p5=LD(5), p6=LD(6), p7=LD(7);
    for (int i = 0; i < cnt; i += 4){
      float4 n0=LD(i+8), n1=LD(i+9), n2=LD(i+10), n3=LD(i+11);
      STEP(p0, true);
      STEP(p1, i+1 < cnt);
      STEP(p2, i+2 < cnt);
      STEP(p3, i+3 < cnt);
      p0=p4; p1=p5; p2=p6; p3=p7;
      p4=n0; p5=n1; p6=n2; p7=n3;
    }
  }
  float invd = (s1 > s0) ? 1.f/den : 0.f;
  float4 b4 = ((const float4*)bias)[lane];
  float rx = fmaf(ax, invd, b4.x);
  float ry = fmaf(ay, invd, b4.y);
  float rz = fmaf(az, invd, b4.z);
  float rw = fmaf(aw, invd, b4.w);
  rx = rx > 0.f ? rx : (__expf(rx) - 1.f);
  ry = ry > 0.f ? ry : (__expf(ry) - 1.f);
  rz = rz > 0.f ? rz : (__expf(rz) - 1.f);
  rw = rw > 0.f ? rw : (__expf(rw) - 1.f);
  ((float4*)out)[(size_t)dst*64 + lane] = make_float4(rx, ry, rz, rw);
}

// ---------------- GATv2 layer 2: one wave/dst, 4 edge groups ----------------
// Wave-uniform trip count K; every __shfl executes at full convergence; per-group
// work predicated on group-uniform (e < cnt). No shuffle reads an inactive lane.
__global__ void k_gat2(const float* __restrict__ xl, const float* __restrict__ xr,
                       const int* __restrict__ row_start, const int* __restrict__ csr,
                       const float* __restrict__ att, const float* __restrict__ bias,
                       float* __restrict__ out, int N){
  int wid = threadIdx.x >> 6, lane = threadIdx.x & 63;
  int dst = blockIdx.x*4 + wid;
  if (dst >= N) return;
  int g = lane >> 4, q = lane & 15;
  const float4* xl4 = (const float4*)xl;
  float4 xr4 = ((const float4*)xr)[(size_t)dst*16 + q];
  float4 at4 = ((const float4*)att)[q];
  int s0 = row_start[dst], s1 = row_start[dst+1];
  float m = -INFINITY, den = 0.f, ax = 0.f, ay = 0.f, az = 0.f, aw = 0.f;
  const float4 Z = make_float4(0.f,0.f,0.f,0.f);

  for (int base = s0; base < s1; base += 64){
    int rem = s1 - base;
    int cnt = rem < 64 ? rem : 64;
    int idxv = (base + lane < s1) ? csr[base + lane] : 0;
    int K = (cnt + 3) >> 2;                      // wave-uniform trip count
    int e0 = g, e1 = g + 4;
    int sA = __shfl(idxv, e0 < cnt ? e0 : 0, 64);
    int sB = __shfl(idxv, e1 < cnt ? e1 : 0, 64);
    float4 vA = (e0 < cnt) ? xl4[(size_t)sA*16 + q] : Z;
    float4 vB = (e1 < cnt) ? xl4[(size_t)sB*16 + q] : Z;
    for (int k = 0; k < K; k++){
      int en = 4*k + 8 + g;
      int sN = __shfl(idxv, en < cnt ? en : 0, 64);   // full convergence
      float4 vN = (en < cnt) ? xl4[(size_t)sN*16 + q] : Z;
      int e = 4*k + g;
      if (e < cnt){                                   // group-uniform
        float4 v = vA;
        float tx = v.x + xr4.x; tx = fmaxf(tx, 0.2f*tx);
        float ty = v.y + xr4.y; ty = fmaxf(ty, 0.2f*ty);
        float tz = v.z + xr4.z; tz = fmaxf(tz, 0.2f*tz);
        float tw = v.w + xr4.w; tw = fmaxf(tw, 0.2f*tw);
        float p = fmaf(tx, at4.x, fmaf(ty, at4.y, fmaf(tz, at4.z, tw*at4.w)));
        p += __shfl_xor(p, 1, 64);
        p += __shfl_xor(p, 2, 64);
        p += __shfl_xor(p, 4, 64);
        p += __shfl_xor(p, 8, 64);
        float mn = fmaxf(m, p);
        float sc = __expf(m - mn);
        float w  = __expf(p - mn);
        den = fmaf(den, sc, w);
        ax = fmaf(ax, sc, w*v.x);
        ay = fmaf(ay, sc, w*v.y);
        az = fmaf(az, sc, w*v.z);
        aw = fmaf(aw, sc, w*v.w);
        m = mn;
      }
      vA = vB; vB = vN;
    }
  }
  // merge 4 edge groups (full convergence here)
  float M2 = fmaxf(m, __shfl_xor(m, 16, 64));
  float Mx = fmaxf(M2, __shfl_xor(M2, 32, 64));
  float sc = (m > -INFINITY) ? __expf(m - Mx) : 0.f;
  den *= sc; ax *= sc; ay *= sc; az *= sc; aw *= sc;
  den += __shfl_xor(den, 16, 64); den += __shfl_xor(den, 32, 64);
  ax  += __shfl_xor(ax, 16, 64);  ax  += __shfl_xor(ax, 32, 64);
  ay  += __shfl_xor(ay, 16, 64);  ay  += __shfl_xor(ay, 32, 64);
  az  += __shfl_xor(az, 16, 64);  az  += __shfl_xor(az, 32, 64);
  aw  += __shfl_xor(aw, 16, 64);  aw  += __shfl_xor(aw, 32, 64);
  float invd = (s1 > s0) ? 1.f/den : 0.f;
  float4 b4 = ((const float4*)bias)[q];
  float rx = fmaf(ax, invd, b4.x);
  float ry = fmaf(ay, invd, b4.y);
  float rz = fmaf(az, invd, b4.z);
  float rw = fmaf(aw, invd, b4.w);
  rx = rx > 0.f ? rx : (__expf(rx) - 1.f);
  ry = ry > 0.f ? ry : (__expf(ry) - 1.f);
  rz = rz > 0.f ? rz : (__expf(rz) - 1.f);
  rw = rw > 0.f ? rw : (__expf(rw) - 1.f);
  if (g == 0) ((float4*)out)[(size_t)dst*16 + q] = make_float4(rx, ry, rz, rw);
}

// ---------------- LSTM weight pack: W4[k][u][4gates], biasc[u][4gates] ----------------
__global__ void k_pack(const float* __restrict__ Wih, const float* __restrict__ Whh,
                       const float* __restrict__ bih, const float* __restrict__ bhh,
                       float* __restrict__ Wih4, float* __restrict__ Whh4,
                       float* __restrict__ biasc){
  int idx = blockIdx.x*256 + threadIdx.x;
  if (idx < 64*256){
    int k = idx >> 8, cu = idx & 255;
    int u = cu >> 2, g = cu & 3;
    Wih4[idx] = Wih[(g*64+u)*64 + k];
    Whh4[idx] = Whh[(g*64+u)*64 + k];
  }
  if (idx < 256){
    int u = idx >> 2, g = idx & 3;
    biasc[idx] = bih[g*64+u] + bhh[g*64+u];
  }
}

// ---------------- LSTM: 6 steps fused, weights staged in LDS slabs ----------------
// Weight traffic is per-BLOCK now (128KB * 6t per block = 480 MB total) instead of
// per-wave (3.8 GB). Inner loop: 4 LDS b128 + 32 FMA per k. 50 KB LDS -> 3 blk/CU.
__global__ __launch_bounds__(512) void k_lstm_slab(
    const float* __restrict__ h2_all,                      // [T][N][64]
    const float* __restrict__ Wih4, const float* __restrict__ Whh4,
    const float* __restrict__ biasc,
    float* __restrict__ hlast, int N){
  __shared__ float WiS[16*256];   // 16 k-slices of packed Wih, 16 KB
  __shared__ float WhS[16*256];
  __shared__ float xT[64*36];     // [k][row32 + pad4]; stride 144B = 9*16B (f4-aligned)
  __shared__ float hT[64*36];
  int tid = threadIdx.x;
  int u = tid & 63, rq = tid >> 6;       // unit, row-quad (8 quads x 4 rows = 32 rows)
  int r0 = blockIdx.x*32;
  for (int idx = tid; idx < 64*36; idx += 512) hT[idx] = 0.f;
  float4 bc = ((const float4*)biasc)[u];
  const float4* Wi4 = (const float4*)Wih4;
  const float4* Wh4 = (const float4*)Whh4;
  float4* WiS4 = (float4*)WiS;
  float4* WhS4 = (float4*)WhS;
  const float4* xT4 = (const float4*)xT;
  const float4* hT4 = (const float4*)hT;
  float c[4] = {0,0,0,0};
  float h[4] = {0,0,0,0};
  for (int t = 0; t < T_STEPS; t++){
    const float* xt = h2_all + (size_t)t*N_NODES*CH;
    #pragma unroll
    for (int it = 0; it < 4; it++){
      int idx = tid + it*512;
      int r = idx >> 6, k = idx & 63;
      int row = r0 + r;
      xT[k*36 + r] = (row < N) ? xt[(size_t)row*64 + k] : 0.f;
    }
    float ai[4], af[4], ag[4], ao[4];
    #pragma unroll
    for (int j = 0; j < 4; j++){ ai[j]=bc.x; af[j]=bc.y; ag[j]=bc.z; ao[j]=bc.w; }
    for (int s = 0; s < 4; s++){
      __syncthreads();               // prev slab consumed; (s==0): xT staged, hT(t-1) visible
      #pragma unroll
      for (int it = 0; it < 2; it++){
        int j = tid + it*512;        // j in [0,1024) = kk*64 + u layout
        WiS4[j] = Wi4[s*1024 + j];
        WhS4[j] = Wh4[s*1024 + j];
      }
      __syncthreads();               // slab ready
      #pragma unroll 8
      for (int kk = 0; kk < 16; kk++){
        int k = s*16 + kk;
        float4 wi = WiS4[kk*64 + u];
        float4 wh = WhS4[kk*64 + u];
        float4 xq = xT4[k*9 + rq];   // broadcast (same addr across wave)
        float4 hq = hT4[k*9 + rq];
        float xv[4] = {xq.x, xq.y, xq.z, xq.w};
        float hv[4] = {hq.x, hq.y, hq.z, hq.w};
        #pragma unroll
        for (int j = 0; j < 4; j++){
          ai[j] = fmaf(xv[j], wi.x, ai[j]); ai[j] = fmaf(hv[j], wh.x, ai[j]);
          af[j] = fmaf(xv[j], wi.y, af[j]); af[j] = fmaf(hv[j], wh.y, af[j]);
          ag[j] = fmaf(xv[j], wi.z, ag[j]); ag[j] = fmaf(hv[j], wh.z, ag[j]);
          ao[j] = fmaf(xv[j], wi.w, ao[j]); ao[j] = fmaf(hv[j], wh.w, ao[j]);
        }
      }
    }
    #pragma unroll
    for (int j = 0; j < 4; j++){
      float I = 1.f/(1.f + __expf(-ai[j]));
      float F = 1.f/(1.f + __expf(-af[j]));
      float O = 1.f/(1.f + __expf(-ao[j]));
      float G = fast_tanh(ag[j]);
      c[j] = fmaf(F, c[j], I*G);
      h[j] = O * fast_tanh(c[j]);
    }
    __syncthreads();                 // all waves done reading hT (inside inner loops)
    #pragma unroll
    for (int j = 0; j < 4; j++) hT[u*36 + rq*4 + j] = h[j];
    // next t's s==0 barrier orders these writes before the next reads
  }
  #pragma unroll
  for (int j = 0; j < 4; j++){
    int row = r0 + rq*4 + j;
    if (row < N) hlast[(size_t)row*64 + u] = h[j];
  }
}

// ---------------- MLP head (fused) ----------------
__global__ void k_mlp(const float* __restrict__ h, const float* __restrict__ Wfc1,
                      const float* __restrict__ bfc1, const float* __restrict__ Wout,
                      const float* __restrict__ bout, float* __restrict__ out, int N){
  int wid = threadIdx.x >> 6, lane = threadIdx.x & 63;
  int row = blockIdx.x*4 + wid;
  if (row >= N) return;
  int j = lane & 31;
  float acc = bfc1[j];
  const float* hr = &h[(size_t)row*64];
  #pragma unroll 8
  for (int k = 0; k < 64; k++) acc = fmaf(hr[k], Wfc1[k*32 + j], acc);
  acc = fmaxf(acc, 0.f);
  float v = acc * Wout[j];
  #pragma unroll
  for (int off = 1; off < 32; off <<= 1) v += __shfl_xor(v, off, 64);
  if (lane == 0) out[row] = v + bout[0];
}

// ---------------- launch ----------------
extern "C" void kernel_launch(void* const* d_in, const int* in_sizes, int n_in,
                              void* d_out, int out_size, void* d_ws, size_t ws_size,
                              hipStream_t stream){
  const float* x    = (const float*)d_in[0];
  const int*   edge = (const int*)  d_in[1];
  const float* Wl1  = (const float*)d_in[2];
  const float* Wr1  = (const float*)d_in[3];
  const float* att1 = (const float*)d_in[4];
  const float* b1   = (const float*)d_in[5];
  const float* Wl2  = (const float*)d_in[6];
  const float* Wr2  = (const float*)d_in[7];
  const float* att2 = (const float*)d_in[8];
  const float* b2   = (const float*)d_in[9];
  const float* Wih  = (const float*)d_in[10];
  const float* Whh  = (const float*)d_in[11];
  const float* bih  = (const float*)d_in[12];
  const float* bhh  = (const float*)d_in[13];
  const float* Wfc1 = (const float*)d_in[14];
  const float* bfc1 = (const float*)d_in[15];
  const float* Wout = (const float*)d_in[16];
  const float* bout = (const float*)d_in[17];
  float* out = (float*)d_out;

  const int N = N_NODES;
  const int E = in_sizes[1] / 2;

  char* p = (char*)d_ws;
  auto alloc = [&](size_t bytes)->char*{ char* q = p; p += (bytes + 255) & ~(size_t)255; return q; };
  int* csr       = (int*)alloc((size_t)E*sizeof(int));
  int* row_start = (int*)alloc((size_t)(N+1)*sizeof(int));
  int* deg       = (int*)alloc((size_t)N*sizeof(int));
  int* cursor    = (int*)alloc((size_t)N*sizeof(int));
  float* xl1    = (float*)alloc((size_t)N*HC*4);
  float* xr1    = (float*)alloc((size_t)N*HC*4);
  float* h1     = (float*)alloc((size_t)N*HC*4);
  float* h2_all = (float*)alloc((size_t)T_STEPS*N*CH*4);
  float* Wih4   = (float*)alloc(64*256*4);
  float* Whh4   = (float*)alloc(64*256*4);
  float* biasc  = (float*)alloc(256*4);
  float* xl2 = xl1;     // reuse: xl1/xr1 dead once h1 is computed
  float* xr2 = xr1;
  float* hlast = h1;    // reuse: h1 dead after last k_gemm2

  const int* srcIdx = edge;       // edge_index[0]
  const int* dstIdx = edge + E;   // edge_index[1]

  hipMemsetAsync(deg,    0, (size_t)N*4, stream);
  hipMemsetAsync(cursor, 0, (size_t)N*4, stream);

  k_count  <<<(E+255)/256, 256, 0, stream>>>(dstIdx, E, deg);
  k_scan   <<<1, 1024, 0, stream>>>(deg, row_start, N);
  k_scatter<<<(E+255)/256, 256, 0, stream>>>(srcIdx, dstIdx, E, row_start, cursor, csr);
  k_sort   <<<(N+3)/4, 256, 0, stream>>>(row_start, csr, N);
  k_pack   <<<64, 256, 0, stream>>>(Wih, Whh, bih, bhh, Wih4, Whh4, biasc);

  for (int t = 0; t < T_STEPS; t++){
    k_gemm1<<<(N+15)/16, 256, 0, stream>>>(x + t*F_INCH, T_STEPS*F_INCH, Wl1, Wr1, xl1, xr1, N);
    k_gat1 <<<(N+3)/4,   256, 0, stream>>>(xl1, xr1, row_start, csr, att1, b1, h1, N);
    k_gemm2<<<(N+15)/16, 256, 0, stream>>>(h1, Wl2, Wr2, xl2, xr2, N);
    k_gat2 <<<(N+3)/4,   256, 0, stream>>>(xl2, xr2, row_start, csr, att2, b2,
                                           h2_all + (size_t)t*N*CH, N);
  }
  k_lstm_slab<<<(N+31)/32, 512, 0, stream>>>(h2_all, Wih4, Whh4, biasc, hlast, N);
  k_mlp<<<(N+3)/4, 256, 0, stream>>>(hlast, Wfc1, bfc1, Wout, bout, out, N);
}